// Round 2
// baseline (912.623 us; speedup 1.0000x reference)
//
#include <hip/hip_runtime.h>

// EdgeModel: out = relu(cat[src(64),dest(64),edge(32)] @ w1[160,128] + b1) @ w2[128,32] + b2
// E = 1,600,000 rows, f32 in/out, bf16 MFMA (threshold 8.8e-2 >> ~3e-2 bf16 err).
//
// R2: swapped-operand GEMM1 -> h is lane-local -> GEMM2 needs NO LDS round-trip.
// LDS = 40KB w1 frags + 512B b1 -> 2 blocks/CU at 512 thr = 16 waves/CU (2x R1).
// GEMM2 uses the MFMA slot-bijection trick: one 16x16x32 contracts two 16-k chunks
// (slots j<4 -> chunk m, j>=4 -> chunk m+4), so only the proven x32 builtin is used.

typedef float  f32x4  __attribute__((ext_vector_type(4)));
typedef short  s16x8  __attribute__((ext_vector_type(8)));

__device__ __forceinline__ unsigned short f2bf(float f) {
    // RTNE float -> bf16 bits
    unsigned int u = __float_as_uint(f);
    u += 0x7FFFu + ((u >> 16) & 1u);
    return (unsigned short)(u >> 16);
}

__global__ __launch_bounds__(512, 4) void edge_mlp(
    const float* __restrict__ src, const float* __restrict__ dst,
    const float* __restrict__ edg, const float* __restrict__ w1,
    const float* __restrict__ b1, const float* __restrict__ w2,
    const float* __restrict__ b2, float* __restrict__ out, int ntiles)
{
    // LDS: w1 fragments 40*64*16B = 40KB, b1 512B. 2 blocks/CU (LDS), 16 waves/CU.
    __shared__ __align__(16) unsigned short w1s[40 * 64 * 8];
    __shared__ __align__(16) float b1s[128];

    const int t    = threadIdx.x;
    const int lane = t & 63;
    const int wid  = t >> 6;      // 0..7
    const int rq   = lane >> 4;   // 0..3
    const int rr   = lane & 15;   // 0..15

    // ---- stage w1 into fragment-order LDS (once per block) ----
    // frag f = kk*8+n ; frag-lane l elem j = w1[kk*32 + (l>>4)*8 + j][n*16 + (l&15)]
    // (A-operand layout for swapped GEMM1: row i = l&15 = hidden sub-col, k = (l>>4)*8+j)
    for (int s = t; s < 40 * 64; s += 512) {
        const int f  = s >> 6, l = s & 63;
        const int kk = f >> 3, n = f & 7;
        const int k0 = kk * 32 + ((l >> 4) << 3);
        const int cl = (n << 4) + (l & 15);
        union { s16x8 v; unsigned short u[8]; } r;
#pragma unroll
        for (int j = 0; j < 8; ++j)
            r.u[j] = f2bf(w1[(k0 + j) * 128 + cl]);
        *reinterpret_cast<s16x8*>(&w1s[s * 8]) = r.v;
    }
    if (t < 128) b1s[t] = b1[t];

    // ---- w2 fragments (slot-bijection layout) + b2 into registers ----
    // slot (q=rq, j): logical k = (j<4 ? m*16 : (m+4)*16) + rq*4 + (j&3)
    s16x8 w2f[4][2];
#pragma unroll
    for (int m = 0; m < 4; ++m)
#pragma unroll
        for (int n2 = 0; n2 < 2; ++n2) {
            union { s16x8 v; unsigned short u[8]; } r;
#pragma unroll
            for (int j = 0; j < 4; ++j) {
                r.u[j]     = f2bf(w2[(m * 16 + rq * 4 + j) * 32 + n2 * 16 + rr]);
                r.u[4 + j] = f2bf(w2[((m + 4) * 16 + rq * 4 + j) * 32 + n2 * 16 + rr]);
            }
            w2f[m][n2] = r.v;
        }
    const float b2c0 = b2[rr];
    const float b2c1 = b2[16 + rr];

    __syncthreads();

    for (int tile = blockIdx.x; tile < ntiles; tile += gridDim.x) {
        const size_t row0 = (size_t)tile * 128 + (size_t)wid * 16;

        // ---- GEMM1 (swapped): acc[n][r] = h[erow=rr][hcol=n*16+rq*4+r] + b1 ----
        f32x4 acc[8];
#pragma unroll
        for (int n = 0; n < 8; ++n)
            acc[n] = *reinterpret_cast<const f32x4*>(&b1s[n * 16 + rq * 4]);

#pragma unroll
        for (int kk = 0; kk < 5; ++kk) {
            const float* sp; int cols, cofs;
            if      (kk == 0) { sp = src; cols = 64; cofs = 0;  }
            else if (kk == 1) { sp = src; cols = 64; cofs = 32; }
            else if (kk == 2) { sp = dst; cols = 64; cofs = 0;  }
            else if (kk == 3) { sp = dst; cols = 64; cofs = 32; }
            else              { sp = edg; cols = 32; cofs = 0;  }

            // B operand (x): lane holds col j = rr (edge row), k = rq*8 + jj
            const float* p = sp + (row0 + rr) * (size_t)cols + cofs + (rq << 3);
            f32x4 v0 = *reinterpret_cast<const f32x4*>(p);
            f32x4 v1 = *reinterpret_cast<const f32x4*>(p + 4);
            union { s16x8 v; unsigned short u[8]; } a;
            a.u[0] = f2bf(v0.x); a.u[1] = f2bf(v0.y);
            a.u[2] = f2bf(v0.z); a.u[3] = f2bf(v0.w);
            a.u[4] = f2bf(v1.x); a.u[5] = f2bf(v1.y);
            a.u[6] = f2bf(v1.z); a.u[7] = f2bf(v1.w);

#pragma unroll
            for (int n = 0; n < 8; ++n) {
                s16x8 wv = *reinterpret_cast<const s16x8*>(&w1s[((kk * 8 + n) * 64 + lane) * 8]);
                acc[n] = __builtin_amdgcn_mfma_f32_16x16x32_bf16(wv, a.v, acc[n], 0, 0, 0);
            }
        }

        // ---- GEMM2: relu+cvt lane-local, slot-bijection x32 MFMA, no LDS ----
        f32x4 acc2[2];
        acc2[0] = (f32x4){b2c0, b2c0, b2c0, b2c0};
        acc2[1] = (f32x4){b2c1, b2c1, b2c1, b2c1};

#pragma unroll
        for (int m = 0; m < 4; ++m) {
            union { s16x8 v; unsigned short u[8]; } hh;
#pragma unroll
            for (int j = 0; j < 4; ++j) {
                hh.u[j]     = f2bf(fmaxf(acc[m][j], 0.0f));      // k chunk m
                hh.u[4 + j] = f2bf(fmaxf(acc[m + 4][j], 0.0f));  // k chunk m+4
            }
            acc2[0] = __builtin_amdgcn_mfma_f32_16x16x32_bf16(hh.v, w2f[m][0], acc2[0], 0, 0, 0);
            acc2[1] = __builtin_amdgcn_mfma_f32_16x16x32_bf16(hh.v, w2f[m][1], acc2[1], 0, 0, 0);
        }

        // store: D2 row = rq*4+j (edge row), col = n2*16+rr (out col)
#pragma unroll
        for (int n2 = 0; n2 < 2; ++n2)
#pragma unroll
            for (int j = 0; j < 4; ++j) {
                const size_t row = row0 + rq * 4 + j;
                out[row * 32 + n2 * 16 + rr] = (n2 == 0 ? acc2[0][j] : acc2[1][j]);
            }
    }
}

// Scalar tail for E % 128 != 0 (not hit for E = 1,600,000; kept for safety)
__global__ void edge_mlp_tail(
    const float* __restrict__ src, const float* __restrict__ dst,
    const float* __restrict__ edg, const float* __restrict__ w1,
    const float* __restrict__ b1, const float* __restrict__ w2,
    const float* __restrict__ b2, float* __restrict__ out,
    long long row0, long long E)
{
    const long long r = row0 + blockIdx.x;
    if (r >= E) return;
    __shared__ float h[128];
    const int t = threadIdx.x;  // 128 threads
    float acc = b1[t];
    for (int k = 0; k < 64; ++k) acc += src[r * 64 + k] * w1[k * 128 + t];
    for (int k = 0; k < 64; ++k) acc += dst[r * 64 + k] * w1[(64 + k) * 128 + t];
    for (int k = 0; k < 32; ++k) acc += edg[r * 32 + k] * w1[(128 + k) * 128 + t];
    h[t] = acc > 0.0f ? acc : 0.0f;
    __syncthreads();
    if (t < 32) {
        float o = b2[t];
        for (int k = 0; k < 128; ++k) o += h[k] * w2[k * 32 + t];
        out[r * 32 + t] = o;
    }
}

extern "C" void kernel_launch(void* const* d_in, const int* in_sizes, int n_in,
                              void* d_out, int out_size, void* d_ws, size_t ws_size,
                              hipStream_t stream)
{
    const float* src = (const float*)d_in[0];
    const float* dst = (const float*)d_in[1];
    const float* edg = (const float*)d_in[2];
    // d_in[3] = u (unused), d_in[4] = batch (unused)
    const float* w1  = (const float*)d_in[5];
    const float* b1  = (const float*)d_in[6];
    const float* w2  = (const float*)d_in[7];
    const float* b2  = (const float*)d_in[8];
    float* out = (float*)d_out;

    const long long E      = (long long)in_sizes[0] / 64;
    const int       ntiles = (int)(E / 128);
    const long long rem    = E - (long long)ntiles * 128;

    if (ntiles > 0) {
        int grid = ntiles < 512 ? ntiles : 512;
        edge_mlp<<<dim3(grid), dim3(512), 0, stream>>>(
            src, dst, edg, w1, b1, w2, b2, out, ntiles);
    }
    if (rem > 0) {
        edge_mlp_tail<<<dim3((unsigned)rem), dim3(128), 0, stream>>>(
            src, dst, edg, w1, b1, w2, b2, out, (long long)ntiles * 128, E);
    }
}